// Round 3
// baseline (1007.288 us; speedup 1.0000x reference)
//
#include <hip/hip_runtime.h>

// S4D: B=8, L=4096, H=1024, N=32 complex modes. f32 in / f32 out.
// R6 resubmit (R7): previous bench run died with "MI355X container failed twice"
// (infra, no compile/verify verdict). Kernel re-audited: transpose-reduce traced
// correct for all 4 quarters, loop trip counts exact, no OOB, no hang hazards.
//
// Design: 4-way mode split in scan_out (8 modes/lane, 4 lanes/h, 4 steps/body) so
// all mode constants (48 regs) stay resident -- R5's VGPR=60 showed the allocator
// rematerialized the 96-float constant set from L1/L2 every iteration rather than
// honor the 128-reg budget. 4x4 transpose-reduce (3 shfl) gives each quarter-lane
// its own timestep -> erf/store unmasked. amdgpu_waves_per_eu(6,6) pins the
// occupancy target so the allocator has no incentive to remat. scan_local: 8-deep
// double-buffered prefetch with peeled tail (no per-step AND/mul address math).

#define B_ 8
#define L_ 4096
#define H_ 1024
#define N_ 32
#define NQ_ 8   // modes per lane (N_/4, 4 lane-groups per h)

// ---------------- kernel A: per-(h,n) mode constants ----------------
// modes[n*H+h] = (w_r, w_i, g_r, g_i); w = exp(dt*A); g = (2 Re C', -2 Im C');
// C' = (C_r + i C_i)*(w-1)/A.  wLc[n*H+h] = w^(Lc).
__global__ void modes_kernel(const float* __restrict__ log_dt,
                             const float* __restrict__ A_real,
                             const float* __restrict__ A_imag,
                             const float* __restrict__ C_real,
                             const float* __restrict__ C_imag,
                             float4* __restrict__ modes,
                             float2* __restrict__ wLc,
                             int log2Lc) {
    int t = blockIdx.x * blockDim.x + threadIdx.x;
    if (t >= H_ * N_) return;
    int h = t / N_, n = t % N_;
    float dt = expf(log_dt[h]);
    float ar = -expf(A_real[t]);
    float ai = A_imag[t];
    float cr = C_real[t];
    float ci = C_imag[t];
    float dr = ar * dt, di = ai * dt;
    float e = expf(dr);
    float sn, cs;
    sincosf(di, &sn, &cs);
    float wr = e * cs, wi = e * sn;
    float inv = 1.0f / (ar * ar + ai * ai);
    float nr = wr - 1.0f, ni = wi;
    float qr = (nr * ar + ni * ai) * inv;
    float qi = (ni * ar - nr * ai) * inv;
    float gr = 2.0f * (cr * qr - ci * qi);
    float gi = -2.0f * (cr * qi + ci * qr);
    modes[n * H_ + h] = make_float4(wr, wi, gr, gi);
    float pr = wr, pi2 = wi;
    for (int i = 0; i < log2Lc; ++i) {
        float t2r = pr * pr - pi2 * pi2;
        float t2i = 2.0f * pr * pi2;
        pr = t2r; pi2 = t2i;
    }
    wLc[n * H_ + h] = make_float2(pr, pi2);
}

// Wave w: bc = w>>6, h-tile = (w&63)*16. Lane: q = lane>>4 (mode quarter, 8 modes),
// k = lane&15 (h within tile). idx = bc*Lc*H + h (since b*L + c*Lc = bc*Lc).

// 4 steps of the state recurrence for 8 modes; optional 4-row prefetch reload.
#define SLOC_BODY(U0, U1, U2, U3, DO_PF) do {                                   \
    _Pragma("unroll")                                                           \
    for (int n = 0; n < NQ_; ++n) {                                             \
        float t1r = fmaf(wr[n], sr[n], fmaf(-wi[n], si[n], (U0)));              \
        float t1i = fmaf(wr[n], si[n], wi[n] * sr[n]);                          \
        float t2r = fmaf(wr[n], t1r, fmaf(-wi[n], t1i, (U1)));                  \
        float t2i = fmaf(wr[n], t1i, wi[n] * t1r);                              \
        float t3r = fmaf(wr[n], t2r, fmaf(-wi[n], t2i, (U2)));                  \
        float t3i = fmaf(wr[n], t2i, wi[n] * t2r);                              \
        float t4r = fmaf(wr[n], t3r, fmaf(-wi[n], t3i, (U3)));                  \
        float t4i = fmaf(wr[n], t3i, wi[n] * t3r);                              \
        sr[n] = t4r; si[n] = t4i;                                               \
    }                                                                           \
    if (DO_PF) {                                                                \
        (U0) = u[pf]; (U1) = u[pf + H_]; (U2) = u[pf + 2u * H_];                \
        (U3) = u[pf + 3u * H_];                                                 \
        pf += 4u * H_;                                                          \
    }                                                                           \
} while (0)

// ---------------- kernel B: local scan per chunk (zero entry state) ----------------
template <int C_>
__global__ __launch_bounds__(256, 8) void scan_local(const float* __restrict__ u,
                                                     const float4* __restrict__ modes,
                                                     float2* __restrict__ states) {
    constexpr int Lc = L_ / C_;
    int t = blockIdx.x * blockDim.x + threadIdx.x;
    int lane = t & 63;
    int w = t >> 6;
    int q = lane >> 4;
    int k = lane & 15;
    int h = (w & 63) * 16 + k;
    int bc = w >> 6;
    int nb = q * NQ_;
    float wr[NQ_], wi[NQ_], sr[NQ_], si[NQ_];
#pragma unroll
    for (int n = 0; n < NQ_; ++n) {
        float4 m = modes[(nb + n) * H_ + h];
        wr[n] = m.x; wi[n] = m.y; sr[n] = 0.0f; si[n] = 0.0f;
    }
    unsigned idx = (unsigned)bc * (unsigned)(Lc * H_) + (unsigned)h;
    float a0 = u[idx];
    float a1 = u[idx + H_];
    float a2 = u[idx + 2u * H_];
    float a3 = u[idx + 3u * H_];
    float b0 = u[idx + 4u * H_];
    float b1 = u[idx + 5u * H_];
    float b2 = u[idx + 6u * H_];
    float b3 = u[idx + 7u * H_];
    unsigned pf = idx + 8u * H_;
    for (int j = 0; j + 8 < Lc; j += 8) {
        SLOC_BODY(a0, a1, a2, a3, 1);
        SLOC_BODY(b0, b1, b2, b3, 1);
    }
    SLOC_BODY(a0, a1, a2, a3, 0);
    SLOC_BODY(b0, b1, b2, b3, 0);
    float2* sp = states + ((size_t)bc * N_ + nb) * H_ + h;
#pragma unroll
    for (int n = 0; n < NQ_; ++n) sp[(size_t)n * H_] = make_float2(sr[n], si[n]);
}

// ---------------- kernel C: cross-chunk scan (in place: local-end -> entry) --------
template <int C_>
__global__ __launch_bounds__(256) void chunk_scan(const float2* __restrict__ wLc,
                                                  float2* __restrict__ states) {
    int t = blockIdx.x * blockDim.x + threadIdx.x;
    int h = t % H_;
    int bn = t / H_;
    int n = bn % N_;
    int b = bn / N_;
    float2 wl = wLc[n * H_ + h];
    float er = 0.0f, ei = 0.0f;
    float2* p0 = states + ((size_t)(b * C_) * N_ + n) * H_ + h;
    const size_t stride = (size_t)N_ * H_;
    float2 nxt = *p0;
#pragma unroll
    for (int c = 0; c < C_; ++c) {
        float2 le = nxt;
        float2* p = p0 + (size_t)c * stride;
        if (c + 1 < C_) nxt = p[stride];  // prefetch next before FMA/store
        *p = make_float2(er, ei);
        float nr2 = fmaf(wl.x, er, fmaf(-wl.y, ei, le.x));
        float ni2 = fmaf(wl.x, ei, fmaf(wl.y, er, le.y));
        er = nr2; ei = ni2;
    }
}

// 4 steps + g-accumulate + 4x4 transpose-reduce + gelu/store (one row per quarter).
#define SOUT_BODY(U0, U1, U2, U3, DO_PF) do {                                   \
    float accA = 0.0f, accB = 0.0f, accC = 0.0f, accD = 0.0f;                   \
    _Pragma("unroll")                                                           \
    for (int n = 0; n < NQ_; ++n) {                                             \
        float t1r = fmaf(wr[n], sr[n], fmaf(-wi[n], si[n], (U0)));              \
        float t1i = fmaf(wr[n], si[n], wi[n] * sr[n]);                          \
        accA = fmaf(gr[n], t1r, fmaf(gi[n], t1i, accA));                        \
        float t2r = fmaf(wr[n], t1r, fmaf(-wi[n], t1i, (U1)));                  \
        float t2i = fmaf(wr[n], t1i, wi[n] * t1r);                              \
        accB = fmaf(gr[n], t2r, fmaf(gi[n], t2i, accB));                        \
        float t3r = fmaf(wr[n], t2r, fmaf(-wi[n], t2i, (U2)));                  \
        float t3i = fmaf(wr[n], t2i, wi[n] * t2r);                              \
        accC = fmaf(gr[n], t3r, fmaf(gi[n], t3i, accC));                        \
        float t4r = fmaf(wr[n], t3r, fmaf(-wi[n], t3i, (U3)));                  \
        float t4i = fmaf(wr[n], t3i, wi[n] * t3r);                              \
        accD = fmaf(gr[n], t4r, fmaf(gi[n], t4i, accD));                        \
        sr[n] = t4r; si[n] = t4i;                                               \
    }                                                                           \
    /* stage 1 (xor 32): pair-sum A with A, B with B across half-groups */      \
    float r0 = hiq ? accC : accA;                                               \
    float r1 = hiq ? accA : accC;                                               \
    float p0 = r0 + __shfl_xor(r1, 32, 64);                                     \
    float r2 = hiq ? accD : accB;                                               \
    float r3 = hiq ? accB : accD;                                               \
    float p1 = r2 + __shfl_xor(r3, 32, 64);                                     \
    /* stage 2 (xor 16): each quarter ends with its own step's total */         \
    float snd = oddq ? p0 : p1;                                                 \
    float bse = oddq ? p1 : p0;                                                 \
    float accS = bse + __shfl_xor(snd, 16, 64);                                 \
    float uv01 = oddq ? (U1) : (U0);                                            \
    float uv23 = oddq ? (U3) : (U2);                                            \
    float uvS = hiq ? uv23 : uv01;                                              \
    float v = fmaf(Dv, uvS, accS);                                              \
    float g = 0.5f * v * (1.0f + erff(v * 0.70710678118654752f));               \
    y[sy] = g;                                                                  \
    sy += 4u * H_;                                                              \
    if (DO_PF) {                                                                \
        (U0) = u[pf]; (U1) = u[pf + H_]; (U2) = u[pf + 2u * H_];                \
        (U3) = u[pf + 3u * H_];                                                 \
        pf += 4u * H_;                                                          \
    }                                                                           \
} while (0)

// ---------------- kernel D: re-scan with entry state, emit gelu(y) ----------------
template <int C_>
__global__ __launch_bounds__(256) __attribute__((amdgpu_waves_per_eu(6, 6)))
void scan_out(const float* __restrict__ u,
              const float4* __restrict__ modes,
              const float2* __restrict__ states,
              const float* __restrict__ Dscal,
              float* __restrict__ y) {
    constexpr int Lc = L_ / C_;
    int t = blockIdx.x * blockDim.x + threadIdx.x;
    int lane = t & 63;
    int w = t >> 6;
    int q = lane >> 4;
    int k = lane & 15;
    int h = (w & 63) * 16 + k;
    int bc = w >> 6;
    int nb = q * NQ_;
    bool hiq = (lane & 32) != 0;   // quarter in {2,3}
    bool oddq = (lane & 16) != 0;  // quarter odd
    float Dv = Dscal[0];
    float wr[NQ_], wi[NQ_], gr[NQ_], gi[NQ_], sr[NQ_], si[NQ_];
#pragma unroll
    for (int n = 0; n < NQ_; ++n) {
        float4 m = modes[(nb + n) * H_ + h];
        wr[n] = m.x; wi[n] = m.y; gr[n] = m.z; gi[n] = m.w;
        float2 e = states[((size_t)bc * N_ + nb + n) * H_ + h];
        sr[n] = e.x; si[n] = e.y;
    }
    unsigned idx = (unsigned)bc * (unsigned)(Lc * H_) + (unsigned)h;
    unsigned sy = idx + (unsigned)(q * H_);
    float a0 = u[idx];
    float a1 = u[idx + H_];
    float a2 = u[idx + 2u * H_];
    float a3 = u[idx + 3u * H_];
    float b0 = u[idx + 4u * H_];
    float b1 = u[idx + 5u * H_];
    float b2 = u[idx + 6u * H_];
    float b3 = u[idx + 7u * H_];
    unsigned pf = idx + 8u * H_;
    for (int j = 0; j + 8 < Lc; j += 8) {
        SOUT_BODY(a0, a1, a2, a3, 1);
        SOUT_BODY(b0, b1, b2, b3, 1);
    }
    SOUT_BODY(a0, a1, a2, a3, 0);
    SOUT_BODY(b0, b1, b2, b3, 0);
}

// ---------------- launcher ----------------
template <int C_>
static void launch_all(const float* u, const float* log_dt, const float* A_real,
                       const float* A_imag, const float* C_real, const float* C_imag,
                       const float* Dscal, float* y, char* ws, hipStream_t stream) {
    float4* modes = (float4*)ws;                        // H*N*16 = 512 KiB
    float2* wLc   = (float2*)(ws + 524288);             // H*N*8  = 256 KiB
    float2* states = (float2*)(ws + 786432);            // B*C*N*H*8
    int log2Lc = 0;
    for (int v = L_ / C_; v > 1; v >>= 1) ++log2Lc;

    constexpr int nwaves = B_ * C_ * (H_ / 16);  // 4 lanes per h
    constexpr int nblocks = nwaves / 4;          // 4 waves per 256-thread block

    modes_kernel<<<(H_ * N_) / 256, 256, 0, stream>>>(log_dt, A_real, A_imag,
                                                      C_real, C_imag, modes, wLc, log2Lc);
    scan_local<C_><<<nblocks, 256, 0, stream>>>(u, modes, states);
    chunk_scan<C_><<<(B_ * N_ * H_) / 256, 256, 0, stream>>>(wLc, states);
    scan_out<C_><<<nblocks, 256, 0, stream>>>(u, modes, states, Dscal, y);
}

extern "C" void kernel_launch(void* const* d_in, const int* in_sizes, int n_in,
                              void* d_out, int out_size, void* d_ws, size_t ws_size,
                              hipStream_t stream) {
    const float* u      = (const float*)d_in[0];
    const float* log_dt = (const float*)d_in[1];
    const float* A_real = (const float*)d_in[2];
    const float* A_imag = (const float*)d_in[3];
    const float* C_real = (const float*)d_in[4];
    const float* C_imag = (const float*)d_in[5];
    const float* Dscal  = (const float*)d_in[6];
    float* y = (float*)d_out;
    char* ws = (char*)d_ws;

    const size_t base = 786432;
    auto need = [&](int C) { return base + (size_t)B_ * C * N_ * H_ * 8; };
    if (ws_size >= need(32)) {
        launch_all<32>(u, log_dt, A_real, A_imag, C_real, C_imag, Dscal, y, ws, stream);
    } else if (ws_size >= need(16)) {
        launch_all<16>(u, log_dt, A_real, A_imag, C_real, C_imag, Dscal, y, ws, stream);
    } else {
        launch_all<8>(u, log_dt, A_real, A_imag, C_real, C_imag, Dscal, y, ws, stream);
    }
}

// Round 4
// 499.305 us; speedup vs baseline: 2.0174x; 2.0174x over previous
//
#include <hip/hip_runtime.h>

// S4D: B=8, L=4096, H=1024, N=32 complex modes. f32 in / f32 out.
// R8: fix R7's catastrophic spill. R7's amdgpu_waves_per_eu(6,6) hard-capped regs
// at 85 < true demand (~100) -> 1.1 GB/dispatch scratch traffic (WRITE_SIZE 1.24 GB
// vs 128 MiB of y), VALUBusy 21%. The 4-way transpose-reduce structure itself
// PASSED on HW. Root issue all session: the allocator either remats invariant mode
// constants from memory every iteration (R5: VGPR=60) or spills (R7). Fix: pin the
// constants with empty asm ("+v") -- non-rematerializable, must stay in VGPRs --
// and give a budget that fits demand: scan_out launch_bounds(256,4) (128 regs,
// need ~90); scan_local launch_bounds(256,6) (85 regs, need ~60).

#define B_ 8
#define L_ 4096
#define H_ 1024
#define N_ 32
#define NQ_ 8   // modes per lane (N_/4, 4 lane-groups per h)

// ---------------- kernel A: per-(h,n) mode constants ----------------
// modes[n*H+h] = (w_r, w_i, g_r, g_i); w = exp(dt*A); g = (2 Re C', -2 Im C');
// C' = (C_r + i C_i)*(w-1)/A.  wLc[n*H+h] = w^(Lc).
__global__ void modes_kernel(const float* __restrict__ log_dt,
                             const float* __restrict__ A_real,
                             const float* __restrict__ A_imag,
                             const float* __restrict__ C_real,
                             const float* __restrict__ C_imag,
                             float4* __restrict__ modes,
                             float2* __restrict__ wLc,
                             int log2Lc) {
    int t = blockIdx.x * blockDim.x + threadIdx.x;
    if (t >= H_ * N_) return;
    int h = t / N_, n = t % N_;
    float dt = expf(log_dt[h]);
    float ar = -expf(A_real[t]);
    float ai = A_imag[t];
    float cr = C_real[t];
    float ci = C_imag[t];
    float dr = ar * dt, di = ai * dt;
    float e = expf(dr);
    float sn, cs;
    sincosf(di, &sn, &cs);
    float wr = e * cs, wi = e * sn;
    float inv = 1.0f / (ar * ar + ai * ai);
    float nr = wr - 1.0f, ni = wi;
    float qr = (nr * ar + ni * ai) * inv;
    float qi = (ni * ar - nr * ai) * inv;
    float gr = 2.0f * (cr * qr - ci * qi);
    float gi = -2.0f * (cr * qi + ci * qr);
    modes[n * H_ + h] = make_float4(wr, wi, gr, gi);
    float pr = wr, pi2 = wi;
    for (int i = 0; i < log2Lc; ++i) {
        float t2r = pr * pr - pi2 * pi2;
        float t2i = 2.0f * pr * pi2;
        pr = t2r; pi2 = t2i;
    }
    wLc[n * H_ + h] = make_float2(pr, pi2);
}

// Wave w: bc = w>>6, h-tile = (w&63)*16. Lane: q = lane>>4 (mode quarter, 8 modes),
// k = lane&15 (h within tile). idx = bc*Lc*H + h (since b*L + c*Lc = bc*Lc).

// 4 steps of the state recurrence for 8 modes; optional 4-row prefetch reload.
#define SLOC_BODY(U0, U1, U2, U3, DO_PF) do {                                   \
    _Pragma("unroll")                                                           \
    for (int n = 0; n < NQ_; ++n) {                                             \
        float t1r = fmaf(wr[n], sr[n], fmaf(-wi[n], si[n], (U0)));              \
        float t1i = fmaf(wr[n], si[n], wi[n] * sr[n]);                          \
        float t2r = fmaf(wr[n], t1r, fmaf(-wi[n], t1i, (U1)));                  \
        float t2i = fmaf(wr[n], t1i, wi[n] * t1r);                              \
        float t3r = fmaf(wr[n], t2r, fmaf(-wi[n], t2i, (U2)));                  \
        float t3i = fmaf(wr[n], t2i, wi[n] * t2r);                              \
        float t4r = fmaf(wr[n], t3r, fmaf(-wi[n], t3i, (U3)));                  \
        float t4i = fmaf(wr[n], t3i, wi[n] * t3r);                              \
        sr[n] = t4r; si[n] = t4i;                                               \
    }                                                                           \
    if (DO_PF) {                                                                \
        (U0) = u[pf]; (U1) = u[pf + H_]; (U2) = u[pf + 2u * H_];                \
        (U3) = u[pf + 3u * H_];                                                 \
        pf += 4u * H_;                                                          \
    }                                                                           \
} while (0)

// ---------------- kernel B: local scan per chunk (zero entry state) ----------------
template <int C_>
__global__ __launch_bounds__(256, 6) void scan_local(const float* __restrict__ u,
                                                     const float4* __restrict__ modes,
                                                     float2* __restrict__ states) {
    constexpr int Lc = L_ / C_;
    int t = blockIdx.x * blockDim.x + threadIdx.x;
    int lane = t & 63;
    int w = t >> 6;
    int q = lane >> 4;
    int k = lane & 15;
    int h = (w & 63) * 16 + k;
    int bc = w >> 6;
    int nb = q * NQ_;
    float wr[NQ_], wi[NQ_], sr[NQ_], si[NQ_];
#pragma unroll
    for (int n = 0; n < NQ_; ++n) {
        float4 m = modes[(nb + n) * H_ + h];
        wr[n] = m.x; wi[n] = m.y; sr[n] = 0.0f; si[n] = 0.0f;
    }
#pragma unroll
    for (int n = 0; n < NQ_; ++n) {
        // pin: non-rematerializable -> allocator must keep these resident
        asm("" : "+v"(wr[n]), "+v"(wi[n]));
    }
    unsigned idx = (unsigned)bc * (unsigned)(Lc * H_) + (unsigned)h;
    float a0 = u[idx];
    float a1 = u[idx + H_];
    float a2 = u[idx + 2u * H_];
    float a3 = u[idx + 3u * H_];
    float b0 = u[idx + 4u * H_];
    float b1 = u[idx + 5u * H_];
    float b2 = u[idx + 6u * H_];
    float b3 = u[idx + 7u * H_];
    unsigned pf = idx + 8u * H_;
    for (int j = 0; j + 8 < Lc; j += 8) {
        SLOC_BODY(a0, a1, a2, a3, 1);
        SLOC_BODY(b0, b1, b2, b3, 1);
    }
    SLOC_BODY(a0, a1, a2, a3, 0);
    SLOC_BODY(b0, b1, b2, b3, 0);
    float2* sp = states + ((size_t)bc * N_ + nb) * H_ + h;
#pragma unroll
    for (int n = 0; n < NQ_; ++n) sp[(size_t)n * H_] = make_float2(sr[n], si[n]);
}

// ---------------- kernel C: cross-chunk scan (in place: local-end -> entry) --------
template <int C_>
__global__ __launch_bounds__(256) void chunk_scan(const float2* __restrict__ wLc,
                                                  float2* __restrict__ states) {
    int t = blockIdx.x * blockDim.x + threadIdx.x;
    int h = t % H_;
    int bn = t / H_;
    int n = bn % N_;
    int b = bn / N_;
    float2 wl = wLc[n * H_ + h];
    float er = 0.0f, ei = 0.0f;
    float2* p0 = states + ((size_t)(b * C_) * N_ + n) * H_ + h;
    const size_t stride = (size_t)N_ * H_;
    float2 nxt = *p0;
#pragma unroll
    for (int c = 0; c < C_; ++c) {
        float2 le = nxt;
        float2* p = p0 + (size_t)c * stride;
        if (c + 1 < C_) nxt = p[stride];  // prefetch next before FMA/store
        *p = make_float2(er, ei);
        float nr2 = fmaf(wl.x, er, fmaf(-wl.y, ei, le.x));
        float ni2 = fmaf(wl.x, ei, fmaf(wl.y, er, le.y));
        er = nr2; ei = ni2;
    }
}

// 4 steps + g-accumulate + 4x4 transpose-reduce + gelu/store (one row per quarter).
#define SOUT_BODY(U0, U1, U2, U3, DO_PF) do {                                   \
    float accA = 0.0f, accB = 0.0f, accC = 0.0f, accD = 0.0f;                   \
    _Pragma("unroll")                                                           \
    for (int n = 0; n < NQ_; ++n) {                                             \
        float t1r = fmaf(wr[n], sr[n], fmaf(-wi[n], si[n], (U0)));              \
        float t1i = fmaf(wr[n], si[n], wi[n] * sr[n]);                          \
        accA = fmaf(gr[n], t1r, fmaf(gi[n], t1i, accA));                        \
        float t2r = fmaf(wr[n], t1r, fmaf(-wi[n], t1i, (U1)));                  \
        float t2i = fmaf(wr[n], t1i, wi[n] * t1r);                              \
        accB = fmaf(gr[n], t2r, fmaf(gi[n], t2i, accB));                        \
        float t3r = fmaf(wr[n], t2r, fmaf(-wi[n], t2i, (U2)));                  \
        float t3i = fmaf(wr[n], t2i, wi[n] * t2r);                              \
        accC = fmaf(gr[n], t3r, fmaf(gi[n], t3i, accC));                        \
        float t4r = fmaf(wr[n], t3r, fmaf(-wi[n], t3i, (U3)));                  \
        float t4i = fmaf(wr[n], t3i, wi[n] * t3r);                              \
        accD = fmaf(gr[n], t4r, fmaf(gi[n], t4i, accD));                        \
        sr[n] = t4r; si[n] = t4i;                                               \
    }                                                                           \
    /* stage 1 (xor 32): pair-sum A with A, B with B across half-groups */      \
    float r0 = hiq ? accC : accA;                                               \
    float r1 = hiq ? accA : accC;                                               \
    float p0 = r0 + __shfl_xor(r1, 32, 64);                                     \
    float r2 = hiq ? accD : accB;                                               \
    float r3 = hiq ? accB : accD;                                               \
    float p1 = r2 + __shfl_xor(r3, 32, 64);                                     \
    /* stage 2 (xor 16): each quarter ends with its own step's total */         \
    float snd = oddq ? p0 : p1;                                                 \
    float bse = oddq ? p1 : p0;                                                 \
    float accS = bse + __shfl_xor(snd, 16, 64);                                 \
    float uv01 = oddq ? (U1) : (U0);                                            \
    float uv23 = oddq ? (U3) : (U2);                                            \
    float uvS = hiq ? uv23 : uv01;                                              \
    float v = fmaf(Dv, uvS, accS);                                              \
    float g = 0.5f * v * (1.0f + erff(v * 0.70710678118654752f));               \
    y[sy] = g;                                                                  \
    sy += 4u * H_;                                                              \
    if (DO_PF) {                                                                \
        (U0) = u[pf]; (U1) = u[pf + H_]; (U2) = u[pf + 2u * H_];                \
        (U3) = u[pf + 3u * H_];                                                 \
        pf += 4u * H_;                                                          \
    }                                                                           \
} while (0)

// ---------------- kernel D: re-scan with entry state, emit gelu(y) ----------------
template <int C_>
__global__ __launch_bounds__(256, 4)
void scan_out(const float* __restrict__ u,
              const float4* __restrict__ modes,
              const float2* __restrict__ states,
              const float* __restrict__ Dscal,
              float* __restrict__ y) {
    constexpr int Lc = L_ / C_;
    int t = blockIdx.x * blockDim.x + threadIdx.x;
    int lane = t & 63;
    int w = t >> 6;
    int q = lane >> 4;
    int k = lane & 15;
    int h = (w & 63) * 16 + k;
    int bc = w >> 6;
    int nb = q * NQ_;
    bool hiq = (lane & 32) != 0;   // quarter in {2,3}
    bool oddq = (lane & 16) != 0;  // quarter odd
    float Dv = Dscal[0];
    float wr[NQ_], wi[NQ_], gr[NQ_], gi[NQ_], sr[NQ_], si[NQ_];
#pragma unroll
    for (int n = 0; n < NQ_; ++n) {
        float4 m = modes[(nb + n) * H_ + h];
        wr[n] = m.x; wi[n] = m.y; gr[n] = m.z; gi[n] = m.w;
        float2 e = states[((size_t)bc * N_ + nb + n) * H_ + h];
        sr[n] = e.x; si[n] = e.y;
    }
#pragma unroll
    for (int n = 0; n < NQ_; ++n) {
        // pin: non-rematerializable -> allocator must keep these resident
        asm("" : "+v"(wr[n]), "+v"(wi[n]), "+v"(gr[n]), "+v"(gi[n]));
    }
    unsigned idx = (unsigned)bc * (unsigned)(Lc * H_) + (unsigned)h;
    unsigned sy = idx + (unsigned)(q * H_);
    float a0 = u[idx];
    float a1 = u[idx + H_];
    float a2 = u[idx + 2u * H_];
    float a3 = u[idx + 3u * H_];
    float b0 = u[idx + 4u * H_];
    float b1 = u[idx + 5u * H_];
    float b2 = u[idx + 6u * H_];
    float b3 = u[idx + 7u * H_];
    unsigned pf = idx + 8u * H_;
    for (int j = 0; j + 8 < Lc; j += 8) {
        SOUT_BODY(a0, a1, a2, a3, 1);
        SOUT_BODY(b0, b1, b2, b3, 1);
    }
    SOUT_BODY(a0, a1, a2, a3, 0);
    SOUT_BODY(b0, b1, b2, b3, 0);
}

// ---------------- launcher ----------------
template <int C_>
static void launch_all(const float* u, const float* log_dt, const float* A_real,
                       const float* A_imag, const float* C_real, const float* C_imag,
                       const float* Dscal, float* y, char* ws, hipStream_t stream) {
    float4* modes = (float4*)ws;                        // H*N*16 = 512 KiB
    float2* wLc   = (float2*)(ws + 524288);             // H*N*8  = 256 KiB
    float2* states = (float2*)(ws + 786432);            // B*C*N*H*8
    int log2Lc = 0;
    for (int v = L_ / C_; v > 1; v >>= 1) ++log2Lc;

    constexpr int nwaves = B_ * C_ * (H_ / 16);  // 4 lanes per h
    constexpr int nblocks = nwaves / 4;          // 4 waves per 256-thread block

    modes_kernel<<<(H_ * N_) / 256, 256, 0, stream>>>(log_dt, A_real, A_imag,
                                                      C_real, C_imag, modes, wLc, log2Lc);
    scan_local<C_><<<nblocks, 256, 0, stream>>>(u, modes, states);
    chunk_scan<C_><<<(B_ * N_ * H_) / 256, 256, 0, stream>>>(wLc, states);
    scan_out<C_><<<nblocks, 256, 0, stream>>>(u, modes, states, Dscal, y);
}

extern "C" void kernel_launch(void* const* d_in, const int* in_sizes, int n_in,
                              void* d_out, int out_size, void* d_ws, size_t ws_size,
                              hipStream_t stream) {
    const float* u      = (const float*)d_in[0];
    const float* log_dt = (const float*)d_in[1];
    const float* A_real = (const float*)d_in[2];
    const float* A_imag = (const float*)d_in[3];
    const float* C_real = (const float*)d_in[4];
    const float* C_imag = (const float*)d_in[5];
    const float* Dscal  = (const float*)d_in[6];
    float* y = (float*)d_out;
    char* ws = (char*)d_ws;

    const size_t base = 786432;
    auto need = [&](int C) { return base + (size_t)B_ * C * N_ * H_ * 8; };
    if (ws_size >= need(32)) {
        launch_all<32>(u, log_dt, A_real, A_imag, C_real, C_imag, Dscal, y, ws, stream);
    } else if (ws_size >= need(16)) {
        launch_all<16>(u, log_dt, A_real, A_imag, C_real, C_imag, Dscal, y, ws, stream);
    } else {
        launch_all<8>(u, log_dt, A_real, A_imag, C_real, C_imag, Dscal, y, ws, stream);
    }
}